// Round 4
// baseline (1366.111 us; speedup 1.0000x reference)
//
#include <hip/hip_runtime.h>
#include <math.h>

// Bloom attention block. Inputs/outputs fp32; bf16 MFMA internally.
// B=1, S=2048, HID=4096, NH=32, HD=128.
// Pipeline: fp32->bf16 convert -> QKV GEMM (32x32x16 MFMA, writes Q/K compact
// + V transposed) -> barrier-free flash attention -> dense GEMM.

typedef __attribute__((ext_vector_type(8))) short short8;
typedef __attribute__((ext_vector_type(4))) float floatx4;
typedef __attribute__((ext_vector_type(16))) float floatx16;
typedef __attribute__((ext_vector_type(4))) unsigned short ushort4v;

#define S_LEN 2048
#define HID_DIM 4096
#define NHEADS 32
#define HDIM 128
#define QKV_N 12288
#define QK_STRIDE 8192            // compact [S][NH*256] Q/K buffer
#define INV_NORM 0.08838834764831845f  // 1/sqrt(128)

__device__ __forceinline__ unsigned short f2bf(float f) {
    union { float f; unsigned int i; } v; v.f = f;
    unsigned int u = v.i;
    return (unsigned short)((u + 0x7fffu + ((u >> 16) & 1u)) >> 16);
}

// async 16B/lane global->LDS (lds dest = wave-uniform base + lane*16)
typedef __attribute__((address_space(1))) unsigned int guint;
typedef __attribute__((address_space(3))) unsigned int luint;
__device__ __forceinline__ void gl_lds16(const unsigned short* g, unsigned short* l) {
    __builtin_amdgcn_global_load_lds((guint*)g, (luint*)l, 16, 0, 0);
}

// ---------------------------------------------------------------------------
// fp32 -> bf16 (RNE), 8 elems/thread, exact grids
// ---------------------------------------------------------------------------
__global__ __launch_bounds__(256) void cvt_bf16(
    const float* __restrict__ src, unsigned short* __restrict__ dst)
{
    size_t i = ((size_t)blockIdx.x * 256 + threadIdx.x) * 8;
    float4 x = *(const float4*)(src + i);
    float4 y = *(const float4*)(src + i + 4);
    union { unsigned u[4]; short8 s; } r;
    r.u[0] = (unsigned)f2bf(x.x) | ((unsigned)f2bf(x.y) << 16);
    r.u[1] = (unsigned)f2bf(x.z) | ((unsigned)f2bf(x.w) << 16);
    r.u[2] = (unsigned)f2bf(y.x) | ((unsigned)f2bf(y.y) << 16);
    r.u[3] = (unsigned)f2bf(y.z) | ((unsigned)f2bf(y.w) << 16);
    *(short8*)(dst + i) = r.s;
}

// ---------------------------------------------------------------------------
// GEMM: C[m][n] = sum_k A[m][k]*B[n][k] + bias[n]  (bf16 in, 128x128 tile,
// BK=64, 4 waves 2x2 of 64x64, each 2x2 of 32x32x16 MFMA).
// Staging via global_load_lds(16B) into unpadded LDS with XOR chunk swizzle
// on the GLOBAL address (measured 0 bank conflicts with this pattern).
// A/B operand layout: m(or n)=lane&31, k=(lane>>5)*8+j.
// C layout: col=lane&31, row=(reg&3)+8*(reg>>2)+4*(lane>>5)  [m74/m101].
// MODE 0: fp32 out [M][N].  MODE 1: QKV — Q/K to compact [S][8192] bf16,
// V written transposed to vt[h][d][s] (block-uniform: 384 = 3*128).
// ---------------------------------------------------------------------------
template <int MODE>
__global__ __launch_bounds__(256) void gemm_bt(
    const unsigned short* __restrict__ A,
    const unsigned short* __restrict__ B,
    const float* __restrict__ bias,
    unsigned short* __restrict__ Cq,
    float* __restrict__ Cf,
    unsigned short* __restrict__ vt,
    int M, int N, int K)
{
    __shared__ unsigned short a_lds[128 * 64];
    __shared__ unsigned short b_lds[128 * 64];
    int t = threadIdx.x;
    int w = t >> 6, lane = t & 63;
    int l31 = lane & 31, half = lane >> 5, l7 = lane & 7;
    int mb = blockIdx.y * 128, nb = blockIdx.x * 128;
    int wm = (w >> 1) * 64, wn = (w & 1) * 64;

    // staging: lane ℓ covers row ℓ/8 of its wave's 8-row stripe, physical
    // chunk ℓ%8; global chunk = (ℓ%8)^(row%8)  (XOR swizzle)
    int lr = lane >> 3;
    int lcol = (l7 ^ lr) * 8;
    const unsigned short* pa = A + (size_t)(mb + w * 32 + lr) * K + lcol;
    const unsigned short* pb = B + (size_t)(nb + w * 32 + lr) * K + lcol;
    unsigned short* la = &a_lds[(w * 32) * 64];
    unsigned short* lb = &b_lds[(w * 32) * 64];

    floatx16 acc[2][2];
    for (int i = 0; i < 2; i++)
        for (int j = 0; j < 2; j++) acc[i][j] = (floatx16)0.0f;

    for (int k0 = 0; k0 < K; k0 += 64) {
        for (int it = 0; it < 4; it++) {
            gl_lds16(pa + k0 + (size_t)it * 8 * K, la + it * 8 * 64);
            gl_lds16(pb + k0 + (size_t)it * 8 * K, lb + it * 8 * 64);
        }
        __syncthreads();
        for (int ks = 0; ks < 4; ks++) {   // K=16 per MFMA
            int chunk = ks * 2 + half;     // global 8-elem chunk 0..7
            short8 af[2], bfr[2];
            for (int i = 0; i < 2; i++) {
                int r = wm + i * 32 + l31;
                af[i] = *(const short8*)&a_lds[r * 64 + ((chunk ^ (r & 7)) * 8)];
            }
            for (int j = 0; j < 2; j++) {
                int r = wn + j * 32 + l31;
                bfr[j] = *(const short8*)&b_lds[r * 64 + ((chunk ^ (r & 7)) * 8)];
            }
            for (int i = 0; i < 2; i++)
                for (int j = 0; j < 2; j++)
                    acc[i][j] = __builtin_amdgcn_mfma_f32_32x32x16_bf16(af[i], bfr[j], acc[i][j], 0, 0, 0);
        }
        __syncthreads();
    }

    if (MODE == 1) {
        int type = blockIdx.x % 3;   // 0=Q 1=K 2=V (384 = 3*128)
        int h = blockIdx.x / 3;
        if (type == 2) {
            for (int j = 0; j < 2; j++) {
                int local = wn + j * 32 + l31;
                float bv = bias[nb + local];
                unsigned short* vp = vt + ((size_t)h * HDIM + local) * S_LEN;
                for (int i = 0; i < 2; i++)
                    for (int g = 0; g < 4; g++) {
                        int rowbase = mb + wm + i * 32 + g * 8 + 4 * half;
                        ushort4v pk;
                        for (int r = 0; r < 4; r++) pk[r] = f2bf(acc[i][j][g * 4 + r] + bv);
                        *(ushort4v*)&vp[rowbase] = pk;
                    }
            }
        } else {
            size_t colbase = (size_t)h * 256 + type * 128;
            for (int j = 0; j < 2; j++) {
                int local = wn + j * 32 + l31;
                float bv = bias[nb + local];
                for (int i = 0; i < 2; i++)
                    for (int g = 0; g < 4; g++) {
                        int rowbase = mb + wm + i * 32 + g * 8 + 4 * half;
                        for (int r = 0; r < 4; r++)
                            Cq[(size_t)(rowbase + r) * QK_STRIDE + colbase + local] =
                                f2bf(acc[i][j][g * 4 + r] + bv);
                    }
            }
        }
    } else {
        for (int j = 0; j < 2; j++) {
            int col = nb + wn + j * 32 + l31;
            float bv = bias[col];
            for (int i = 0; i < 2; i++)
                for (int g = 0; g < 4; g++) {
                    int rowbase = mb + wm + i * 32 + g * 8 + 4 * half;
                    for (int r = 0; r < 4; r++)
                        Cf[(size_t)(rowbase + r) * N + col] = acc[i][j][g * 4 + r] + bv;
                }
        }
    }
}

// ---------------------------------------------------------------------------
// Barrier-free flash attention, causal + alibi. One block per (q-tile, head);
// grid.x = qtile so consecutive blocks share a head's K/V in L2.
// 4 waves x 16 q-rows; K-tiles of 64 keys. K/V fragments read DIRECTLY from
// global (16 rows x 64B per wave-load — 64B-granular, L1/L2 served).
// No __syncthreads anywhere. Row-sum l accumulated via ones-column MFMA.
// ---------------------------------------------------------------------------
__global__ __launch_bounds__(256) void attn_flash(
    const unsigned short* __restrict__ qk,      // [S][8192] bf16
    const unsigned short* __restrict__ vt,      // [NH][128][S] bf16
    const float* __restrict__ alibi,            // [NH][S] fp32
    unsigned short* __restrict__ ctx)           // [S][4096] bf16
{
    __shared__ unsigned short p_lds[4 * 16 * 72];   // per-wave P transform

    int qtile = blockIdx.x, h = blockIdx.y;
    int qb = qtile * 64;
    int t = threadIdx.x;
    int w = t >> 6, lane = t & 63, quad = lane >> 4, l15 = lane & 15;
    int qoff = h * 256;

    // Q fragments (A-layout: m=l15, k=quad*8+j) for this wave's 16 q rows
    short8 qf[4];
    {
        const unsigned short* qp = qk + (size_t)(qb + w * 16 + l15) * QK_STRIDE + qoff;
        for (int ks = 0; ks < 4; ks++)
            qf[ks] = *(const short8*)&qp[ks * 32 + quad * 8];
    }

    // per-lane base pointers for direct K/V fragment loads
    const unsigned short* kbase = qk + qoff + 128 + (size_t)l15 * QK_STRIDE + quad * 8;
    const unsigned short* vbase = vt + ((size_t)h * HDIM + l15) * S_LEN + quad * 8;

    // ones B-fragment: column 0 (n=0) = 1.0 for all k -> o8 = P row-sums
    short8 ones;
    {
        union { unsigned u[4]; short8 s; } ov;
        unsigned ob = (l15 == 0) ? 0x3F803F80u : 0u;
        ov.u[0] = ob; ov.u[1] = ob; ov.u[2] = ob; ov.u[3] = ob;
        ones = ov.s;
    }

    floatx4 o[8], o8;
    for (int j = 0; j < 8; j++) o[j] = (floatx4)0.0f;
    o8 = (floatx4)0.0f;
    float m_prev[4];
    for (int r = 0; r < 4; r++) m_prev[r] = -INFINITY;

    int ntiles = qtile + 1;
    for (int tile = 0; tile < ntiles; tile++) {
        int kb = tile * 64;
        // S = Q K^T : K fragments straight from global
        floatx4 s[4];
        for (int j = 0; j < 4; j++) s[j] = (floatx4)0.0f;
        const unsigned short* kt = kbase + (size_t)kb * QK_STRIDE;
        for (int ks = 0; ks < 4; ks++)
            for (int j = 0; j < 4; j++) {
                short8 bfr = *(const short8*)(kt + (size_t)j * 16 * QK_STRIDE + ks * 32);
                s[j] = __builtin_amdgcn_mfma_f32_16x16x32_bf16(qf[ks], bfr, s[j], 0, 0, 0);
            }

        // scale + alibi (+ causal mask on the diagonal tile only)
        bool last = (tile == ntiles - 1);
        float sv[4][4];
        for (int j = 0; j < 4; j++) {
            int kcol = kb + j * 16 + l15;
            float al = alibi[h * S_LEN + kcol];
            for (int r = 0; r < 4; r++) {
                int qrow = qb + w * 16 + quad * 4 + r;
                float x = s[j][r] * INV_NORM + al;
                sv[j][r] = (!last || kcol <= qrow) ? x : -INFINITY;
            }
        }

        // online softmax: running max only (sum comes from ones-MFMA)
        float p[4][4];
        for (int r = 0; r < 4; r++) {
            float mt = fmaxf(fmaxf(sv[0][r], sv[1][r]), fmaxf(sv[2][r], sv[3][r]));
            for (int off = 1; off < 16; off <<= 1)
                mt = fmaxf(mt, __shfl_xor(mt, off, 64));
            float m_new = fmaxf(m_prev[r], mt);
            float alpha = __expf(m_prev[r] - m_new);   // exp(-inf)=0 first tile
            for (int j = 0; j < 4; j++)
                p[j][r] = __expf(sv[j][r] - m_new);    // masked -> 0
            m_prev[r] = m_new;
            for (int j = 0; j < 8; j++) o[j][r] *= alpha;
            o8[r] *= alpha;
        }

        // P (C-layout) -> LDS -> A-layout fragments (per-wave region, no barrier)
        unsigned short* pb = &p_lds[w * 16 * 72];
        for (int j = 0; j < 4; j++)
            for (int r = 0; r < 4; r++)
                pb[(quad * 4 + r) * 72 + j * 16 + l15] = f2bf(p[j][r]);

        // O += P V : V fragments straight from global (vt is [d][s])
        const unsigned short* vtb = vbase + kb;
        for (int ks = 0; ks < 2; ks++) {
            short8 ap = *(const short8*)&pb[l15 * 72 + ks * 32 + quad * 8];
            for (int j = 0; j < 8; j++) {
                short8 bv = *(const short8*)(vtb + (size_t)j * 16 * S_LEN + ks * 32);
                o[j] = __builtin_amdgcn_mfma_f32_16x16x32_bf16(ap, bv, o[j], 0, 0, 0);
            }
            o8 = __builtin_amdgcn_mfma_f32_16x16x32_bf16(ap, ones, o8, 0, 0, 0);
        }
    }

    // normalize (l = row-sum from o8 col 0, lane l15==0 of each 16-group)
    for (int r = 0; r < 4; r++) {
        float l = __shfl(o8[r], 0, 16);
        float linv = 1.0f / l;
        int qrow = qb + w * 16 + quad * 4 + r;
        unsigned short* op = ctx + (size_t)qrow * HID_DIM + h * HDIM;
        for (int j = 0; j < 8; j++)
            op[j * 16 + l15] = f2bf(o[j][r] * linv);
    }
}

extern "C" void kernel_launch(void* const* d_in, const int* in_sizes, int n_in,
                              void* d_out, int out_size, void* d_ws, size_t ws_size,
                              hipStream_t stream) {
    const float* hidden  = (const float*)d_in[0];  // [1,2048,4096] fp32
    const float* alibi   = (const float*)d_in[1];  // [32,1,2048]   fp32
    const float* w_qkv   = (const float*)d_in[2];  // [12288,4096]  fp32
    const float* b_qkv   = (const float*)d_in[3];  // [12288]       fp32
    const float* w_dense = (const float*)d_in[4];  // [4096,4096]   fp32
    const float* b_dense = (const float*)d_in[5];  // [4096]        fp32
    float* out = (float*)d_out;                    // [2048,4096]   fp32

    // ws layout (ushort elements), overlays safe by stream order:
    unsigned short* ws    = (unsigned short*)d_ws;
    unsigned short* wq_bf = ws;                                     // 50,331,648
    unsigned short* fused = ws + (size_t)50331648;                  // [S][8192]
    unsigned short* vt    = fused + (size_t)S_LEN * QK_STRIDE;      // [NH][128][S]
    unsigned short* hbf   = vt + (size_t)NHEADS * HDIM * S_LEN;     // hidden bf16
    unsigned short* ctx   = hbf;   // overlay: hbf dead after QKV GEMM
    unsigned short* wd_bf = wq_bf; // overlay: wq_bf dead after QKV GEMM

    dim3 blk(256);
    cvt_bf16<<<dim3(4096),  blk, 0, stream>>>(hidden,  hbf);
    cvt_bf16<<<dim3(24576), blk, 0, stream>>>(w_qkv,   wq_bf);
    // QKV projection -> fused Q/K + transposed V
    gemm_bt<1><<<dim3(QKV_N / 128, S_LEN / 128), blk, 0, stream>>>(
        hbf, wq_bf, b_qkv, fused, nullptr, vt, S_LEN, QKV_N, HID_DIM);
    // attention (grid.x = qtile so same-head blocks are adjacent in dispatch)
    attn_flash<<<dim3(S_LEN / 64, NHEADS), blk, 0, stream>>>(fused, vt, alibi, ctx);
    cvt_bf16<<<dim3(8192), blk, 0, stream>>>(w_dense, wd_bf);
    // output projection (fp32 out)
    gemm_bt<0><<<dim3(HID_DIM / 128, S_LEN / 128), blk, 0, stream>>>(
        ctx, wd_bf, b_dense, nullptr, out, nullptr, S_LEN, HID_DIM, HID_DIM);
}